// Round 5
// baseline (215.765 us; speedup 1.0000x reference)
//
#include <hip/hip_runtime.h>
#include <hip/hip_fp16.h>
#include <cstdint>
#include <cstddef>

#define BB 4
#define CC 256
#define NN 4096
#define EPS_NORM 2.220446049250313e-16f
#define EPS_MIN 1e-5f

typedef __attribute__((ext_vector_type(8))) short short8;
typedef __attribute__((ext_vector_type(4))) float floatx4;

__device__ __forceinline__ unsigned short f2bf(float f) {
    unsigned u = __float_as_uint(f);
    u += 0x7FFFu + ((u >> 16) & 1u);   // RNE
    return (unsigned short)(u >> 16);
}
__device__ __forceinline__ void async_cp16(const void* g, void* l) {
    __builtin_amdgcn_global_load_lds(
        (const __attribute__((address_space(1))) unsigned int*)g,
        (__attribute__((address_space(3))) unsigned int*)l, 16, 0, 0);
}

// ---- K1: per-channel spatial mean of Y (float4); also zero sums ------------
__global__ void kmean(const float* __restrict__ Y, float* __restrict__ ymean,
                      float* __restrict__ sums) {
    if (blockIdx.x == 0 && threadIdx.x < BB) sums[threadIdx.x] = 0.f;
    int bc = blockIdx.x;  // b*CC + c
    const float4* p = (const float4*)(Y + (size_t)bc * NN);
    float s = 0.f;
    for (int k = threadIdx.x; k < NN / 4; k += 256) {
        float4 v = p[k];
        s += (v.x + v.y) + (v.z + v.w);
    }
    __shared__ float red[256];
    red[threadIdx.x] = s; __syncthreads();
    for (int st = 128; st > 0; st >>= 1) {
        if (threadIdx.x < st) red[threadIdx.x] += red[threadIdx.x + st];
        __syncthreads();
    }
    if (threadIdx.x == 0) ymean[bc] = red[0] * (1.0f / NN);
}

// ------- K2: fused norm + normalize + transpose -> bf16 [B,N,C] -------------
__global__ __launch_bounds__(256)
void kfuse(const float* __restrict__ X, const float* __restrict__ Y,
           const float* __restrict__ ymean,
           unsigned short* __restrict__ XnT, unsigned short* __restrict__ YnT) {
    int b = blockIdx.y >> 1, which = blockIdx.y & 1;
    const float* src = which ? Y : X;
    unsigned short* dst = which ? YnT : XnT;
    int n0 = blockIdx.x * 64;
    int tx = threadIdx.x & 63, ty = threadIdx.x >> 6;
    __shared__ float mean_s[CC];
    __shared__ float red[4][64];
    __shared__ float invn[64];
    __shared__ float tile[64][65];
    mean_s[threadIdx.x] = ymean[b * CC + threadIdx.x];
    __syncthreads();
    float vreg[64];
    float s = 0.f;
    #pragma unroll
    for (int k = 0; k < 64; ++k) {
        int c = ty + 4 * k;
        float v = src[(((size_t)b * CC + c) << 12) + n0 + tx] - mean_s[c];
        vreg[k] = v;
        s += v * v;
    }
    red[ty][tx] = s; __syncthreads();
    if (ty == 0) {
        float t = red[0][tx] + red[1][tx] + red[2][tx] + red[3][tx];
        invn[tx] = 1.0f / (sqrtf(t) + EPS_NORM);
    }
    __syncthreads();
    float inv = invn[tx];
    for (int cb = 0; cb < 4; ++cb) {
        if (cb) __syncthreads();
        #pragma unroll
        for (int kk = 0; kk < 16; ++kk) {
            tile[4 * kk + ty][tx] = vreg[cb * 16 + kk] * inv;
        }
        __syncthreads();
        #pragma unroll
        for (int it = 0; it < 16; ++it) {
            int nl = ty + it * 4;
            dst[((size_t)(b * NN + n0 + nl)) * CC + cb * 64 + tx] = f2bf(tile[tx][nl]);
        }
    }
}

// -------- krow: row-panel GEMM, A-frags in registers, 4-slot B pipeline -----
// Block = 512 thr (8 waves, 2x4), owns i-panel 128 rows x j-half 2048 cols.
// A (128x256) staged once into LDS slots 2-3, fragments hoisted to 128 VGPRs,
// LDS region then recycled as B slots. B rotates through 4 x 32 KiB slots,
// prefetch depth 3, steady s_waitcnt vmcnt(12) (never drained mid-loop).
// MODE 1: row-min of d. MODE 2: row-sum of exp. MODE 3: col-max of t.
template <int MODE>
__global__ __launch_bounds__(512, 2)
void krow(const unsigned short* __restrict__ Aptr, const unsigned short* __restrict__ Bptr,
          const float* __restrict__ rowA, const float* __restrict__ rowB,
          float* __restrict__ partial, float* __restrict__ colpart) {
    const int bid = blockIdx.x;
    const int b = (bid >> 1) & 3;       // xcd = bid&7 -> (b,jh): batch pinned to 2 XCDs
    const int jh = bid & 1;
    const int ip = bid >> 3;            // 0..31
    const int i0 = ip * 128, j0 = jh * 2048;
    const int tid = threadIdx.x, lane = tid & 63, wave = tid >> 6;
    const int wm = wave >> 2, wn = wave & 3, l15 = lane & 15, quad = lane >> 4;

    __shared__ unsigned short Bs[4 * 16384];   // 128 KiB: 4 B-slots (2-3 hold A at start)
    __shared__ float scratch[4096];            // 16 KiB
    __shared__ float2 ab[128];                 // 1 KiB alpha/beta table

    // ---- alpha/beta global loads (drained by prologue __syncthreads) -------
    float a_v = 0.f, b_v = 0.f;
    if (MODE >= 2 && tid < 128) {
        a_v = rowA[b * NN + i0 + tid];
        if (MODE == 3) b_v = rowB[b * NN + i0 + tid];
    }

    const int rl = lane >> 3, pos = lane & 7, cbx = pos ^ rl;

    // ---- stage A (128x256) once into slots 2+3 region ----------------------
    {
        const int kcA = wave >> 1, half = (wave & 1) * 64;
        const unsigned short* gAl = Aptr + ((size_t)b * NN + i0 + half + rl) * CC + kcA * 64 + cbx * 8;
        unsigned short* lA = Bs + 32768 + kcA * 8192 + half * 64;
        #pragma unroll
        for (int seg = 0; seg < 8; ++seg)
            async_cp16(gAl + (size_t)seg * 8 * CC, lA + seg * 8 * 64);
    }

    // ---- B staging: stage s -> slot s&3, 256 rows x 64 k per stage ---------
    const unsigned short* gBl = Bptr + ((size_t)b * NN + j0 + wave * 32 + rl) * CC + cbx * 8;
#define STAGE_B(s) do { \
        const unsigned short* gs_ = gBl + (size_t)((s) >> 2) * 256 * CC + ((s) & 3) * 64; \
        unsigned short* lb_ = Bs + ((s) & 3) * 16384 + wave * 2048; \
        async_cp16(gs_ + (size_t)0 * 8 * CC, lb_ + 0 * 8 * 64); \
        async_cp16(gs_ + (size_t)1 * 8 * CC, lb_ + 1 * 8 * 64); \
        async_cp16(gs_ + (size_t)2 * 8 * CC, lb_ + 2 * 8 * 64); \
        async_cp16(gs_ + (size_t)3 * 8 * CC, lb_ + 3 * 8 * 64); \
    } while (0)

    STAGE_B(0);
    STAGE_B(1);
    __syncthreads();                 // full drain: A + B0 + B1 + a/b loads landed

    if (MODE >= 2 && tid < 128)
        ab[tid] = (MODE == 2) ? make_float2(a_v, 10.0f - a_v)
                              : make_float2(a_v, b_v - a_v);

    // ---- hoist A fragments: 4 kc x 2 kk-halves x 4 m = 32 short8 -----------
    short8 af[4][8];
    #pragma unroll
    for (int kc = 0; kc < 4; ++kc)
        #pragma unroll
        for (int h = 0; h < 2; ++h)
            #pragma unroll
            for (int s = 0; s < 4; ++s)
                af[kc][h * 4 + s] = *(const short8*)&Bs[32768 + kc * 8192 +
                    (wm * 64 + s * 16 + l15) * 64 + (((quad + 4 * h) ^ (l15 & 7)) << 3)];
    __syncthreads();                 // af reads complete; ab visible; A region free
    STAGE_B(2);

    floatx4 acc[4][4];
    #pragma unroll
    for (int ms = 0; ms < 4; ++ms)
        #pragma unroll
        for (int ns = 0; ns < 4; ++ns) acc[ms][ns] = (floatx4){0.f, 0.f, 0.f, 0.f};
    float rm[4][4];
    #pragma unroll
    for (int ms = 0; ms < 4; ++ms)
        #pragma unroll
        for (int r = 0; r < 4; ++r) rm[ms][r] = (MODE == 1) ? 1e30f : 0.f;

    // ---- main loop: 8 j-tiles x 4 kc = 32 steps, slot = kc -----------------
    for (int ut = 0; ut < 8; ++ut) {
        #pragma unroll
        for (int kc = 0; kc < 4; ++kc) {
            const int u = ut * 4 + kc;
            if (u) {
                asm volatile("" ::: "memory");
                __builtin_amdgcn_s_barrier();       // compute(u-1) done -> slot (u+3)&3 free
                asm volatile("" ::: "memory");
            }
            if (u + 3 < 32) STAGE_B(u + 3);
            if (u < 29)      asm volatile("s_waitcnt vmcnt(12)" ::: "memory");
            else if (u == 29) asm volatile("s_waitcnt vmcnt(8)" ::: "memory");
            else if (u == 30) asm volatile("s_waitcnt vmcnt(4)" ::: "memory");
            else              asm volatile("s_waitcnt vmcnt(0)" ::: "memory");
            __builtin_amdgcn_s_barrier();           // every wave's stage(u) landed
            asm volatile("" ::: "memory");

            const unsigned short* Bp = Bs + kc * 16384;
            #pragma unroll
            for (int h = 0; h < 2; ++h) {
                short8 bf[4];
                const int sw = (((quad + 4 * h) ^ (l15 & 7)) << 3);
                #pragma unroll
                for (int s = 0; s < 4; ++s)
                    bf[s] = *(const short8*)&Bp[(wn * 64 + s * 16 + l15) * 64 + sw];
                #pragma unroll
                for (int ms = 0; ms < 4; ++ms)
                    #pragma unroll
                    for (int ns = 0; ns < 4; ++ns)
                        acc[ms][ns] = __builtin_amdgcn_mfma_f32_16x16x32_bf16(
                            af[kc][h * 4 + ms], bf[ns], acc[ms][ns], 0, 0, 0);
            }

            if (kc == 3) {   // j-tile complete: fold and reset acc
                const int jt = ut;
                if (MODE == 1) {
                    #pragma unroll
                    for (int ms = 0; ms < 4; ++ms)
                        #pragma unroll
                        for (int r = 0; r < 4; ++r) {
                            float m = 1.0f - acc[ms][0][r];
                            #pragma unroll
                            for (int ns = 1; ns < 4; ++ns) m = fminf(m, 1.0f - acc[ms][ns][r]);
                            rm[ms][r] = fminf(rm[ms][r], m);
                        }
                } else if (MODE == 2) {
                    #pragma unroll
                    for (int ms = 0; ms < 4; ++ms)
                        #pragma unroll
                        for (int r = 0; r < 4; ++r) {
                            float2 p = ab[wm * 64 + ms * 16 + quad * 4 + r];
                            float s = 0.f;
                            #pragma unroll
                            for (int ns = 0; ns < 4; ++ns)
                                s += __expf(fmaf(p.x, acc[ms][ns][r], p.y));
                            rm[ms][r] += s;
                        }
                } else {
                    #pragma unroll
                    for (int ns = 0; ns < 4; ++ns) {
                        float v = -1e30f;
                        #pragma unroll
                        for (int ms = 0; ms < 4; ++ms)
                            #pragma unroll
                            for (int r = 0; r < 4; ++r) {
                                float2 p = ab[wm * 64 + ms * 16 + quad * 4 + r];
                                v = fmaxf(v, fmaf(p.x, acc[ms][ns][r], p.y));
                            }
                        v = fmaxf(v, __shfl_xor(v, 16));
                        v = fmaxf(v, __shfl_xor(v, 32));
                        if (quad == 0)
                            scratch[((wm * 4 + wn) * 8 + jt) * 64 + ns * 16 + l15] = v;
                    }
                }
                #pragma unroll
                for (int ms = 0; ms < 4; ++ms)
                    #pragma unroll
                    for (int ns = 0; ns < 4; ++ns) acc[ms][ns] = (floatx4){0.f, 0.f, 0.f, 0.f};
            }
        }
    }
#undef STAGE_B

    // ---- block epilogue ----------------------------------------------------
    if (MODE <= 2) {
        #pragma unroll
        for (int ms = 0; ms < 4; ++ms)
            #pragma unroll
            for (int r = 0; r < 4; ++r) {
                float v = rm[ms][r];
                if (MODE == 1) {
                    v = fminf(v, __shfl_xor(v, 1)); v = fminf(v, __shfl_xor(v, 2));
                    v = fminf(v, __shfl_xor(v, 4)); v = fminf(v, __shfl_xor(v, 8));
                } else {
                    v += __shfl_xor(v, 1); v += __shfl_xor(v, 2);
                    v += __shfl_xor(v, 4); v += __shfl_xor(v, 8);
                }
                if (l15 == 0)
                    scratch[(wm * 64 + ms * 16 + quad * 4 + r) * 4 + wn] = v;
            }
        __syncthreads();
        if (tid < 128) {
            float4 q4 = *(const float4*)&scratch[tid * 4];
            float v = (MODE == 1) ? fminf(fminf(q4.x, q4.y), fminf(q4.z, q4.w))
                                  : (q4.x + q4.y) + (q4.z + q4.w);
            partial[((size_t)(b * 2 + jh)) * NN + i0 + tid] = v;
        }
    } else {
        __syncthreads();
        #pragma unroll
        for (int it = 0; it < 4; ++it) {
            int idx = it * 512 + tid;               // 2048 cols
            int jt = idx >> 8, c = idx & 255;
            int wnv = c >> 6, cl = c & 63;
            float v = fmaxf(scratch[((0 * 4 + wnv) * 8 + jt) * 64 + cl],
                            scratch[((1 * 4 + wnv) * 8 + jt) * 64 + cl]);
            colpart[((size_t)(b * 32 + ip)) * NN + j0 + idx] = v;
        }
    }
}

// ---- reduce partial row-min over 2 j-halves -> alpha -----------------------
__global__ void kredA(const float* __restrict__ partial, float* __restrict__ rowA) {
    int idx = blockIdx.x * 256 + threadIdx.x;      // over BB*NN
    int b = idx >> 12, i = idx & (NN - 1);
    float m = fminf(partial[((size_t)(b * 2)) * NN + i],
                    partial[((size_t)(b * 2 + 1)) * NN + i]);
    rowA[idx] = 10.0f / (m + EPS_MIN);
}

// ---- reduce partial row-sum over 2 j-halves -> beta ------------------------
__global__ void kredB(const float* __restrict__ partial, float* __restrict__ rowB) {
    int idx = blockIdx.x * 256 + threadIdx.x;
    int b = idx >> 12, i = idx & (NN - 1);
    float s = partial[((size_t)(b * 2)) * NN + i] +
              partial[((size_t)(b * 2 + 1)) * NN + i];
    rowB[idx] = 10.0f - __logf(s);
}

// ---- reduce colpart over 32 i-panels -> exp -> sum per batch ---------------
__global__ void kredC(const float* __restrict__ colpart, float* __restrict__ sums) {
    int b = blockIdx.y;
    int j = blockIdx.x * 256 + threadIdx.x;
    float m = -1e30f;
    #pragma unroll 4
    for (int p = 0; p < 32; ++p)
        m = fmaxf(m, colpart[((size_t)(b * 32 + p)) * NN + j]);
    float e = __expf(m);
    __shared__ float red[256];
    red[threadIdx.x] = e; __syncthreads();
    for (int st = 128; st > 0; st >>= 1) {
        if (threadIdx.x < st) red[threadIdx.x] += red[threadIdx.x + st];
        __syncthreads();
    }
    if (threadIdx.x == 0) atomicAdd(&sums[b], red[0]);
}

__global__ void kfinal2(const float* __restrict__ sums, float* __restrict__ out) {
    int t = threadIdx.x;
    if (t < BB) out[t] = logf((float)NN) - logf(sums[t]);
}

extern "C" void kernel_launch(void* const* d_in, const int* in_sizes, int n_in,
                              void* d_out, int out_size, void* d_ws, size_t ws_size,
                              hipStream_t stream) {
    const float* X = (const float*)d_in[0];
    const float* Y = (const float*)d_in[1];
    float* out = (float*)d_out;

    char* w = (char*)d_ws;
    float* ymean        = (float*)(w + 0);                  //   4 KiB
    float* sums         = (float*)(w + 4096);               //  tiny
    float* rowA         = (float*)(w + 8192);               //  64 KiB
    float* rowB         = (float*)(w + 73728);              //  64 KiB
    float* partial      = (float*)(w + 139264);             // 128 KiB
    float* colpart      = (float*)(w + 270336);             //   2 MiB
    unsigned short* XnT = (unsigned short*)(w + 2367488);   //   8 MiB
    unsigned short* YnT = (unsigned short*)(w + 10756096);  //   8 MiB (total ~18.3 MiB)

    kmean<<<dim3(BB * CC), 256, 0, stream>>>(Y, ymean, sums);
    kfuse<<<dim3(NN / 64, BB * 2), 256, 0, stream>>>(X, Y, ymean, XnT, YnT);

    dim3 ggrid(256);   // 4b x 32ip x 2jh, XCD-pinned decode in-kernel
    krow<1><<<ggrid, 512, 0, stream>>>(XnT, YnT, rowA, rowB, partial, colpart);
    kredA<<<dim3(BB * NN / 256), 256, 0, stream>>>(partial, rowA);
    krow<2><<<ggrid, 512, 0, stream>>>(XnT, YnT, rowA, rowB, partial, colpart);
    kredB<<<dim3(BB * NN / 256), 256, 0, stream>>>(partial, rowB);
    krow<3><<<ggrid, 512, 0, stream>>>(XnT, YnT, rowA, rowB, partial, colpart);
    kredC<<<dim3(NN / 256, BB), 256, 0, stream>>>(colpart, sums);
    kfinal2<<<dim3(1), 64, 0, stream>>>(sums, out);
}